// Round 7
// baseline (1904.198 us; speedup 1.0000x reference)
//
#include <hip/hip_runtime.h>
#include <math.h>

typedef _Float16 f16;
typedef _Float16 half4 __attribute__((ext_vector_type(4)));
typedef _Float16 half8 __attribute__((ext_vector_type(8)));
typedef float f32x4 __attribute__((ext_vector_type(4)));

#define NK 256
#define LW 249
#define WHS 256          // Wh row stride (f16, zero-padded)
#define TLEN 2000
#define PAD 124
#define NCOPY 8
#define CPL 2328         // elems/copy; dword stride 1164 == 12 mod 32 -> conflict-free b128
#define CPWRITE 2304
#define THREADS 512

// ws layout (bytes)
#define WS_BIASP (NK * WHS * 2)
#define WS_PERM  (WS_BIASP + NK * 4)
#define WS_TM    (WS_PERM + NK * 4)
#define WS_PART  (WS_TM + 64)          // float2 part[2][256][256]

// ---- prep: deterministic rank-sort rows by window size M, permuted f16 W ----
__global__ __launch_bounds__(256) void prep(const float* __restrict__ W,
                                            const float* __restrict__ bias,
                                            f16* __restrict__ Wh,
                                            float* __restrict__ biasP,
                                            int* __restrict__ perm,
                                            int* __restrict__ tileM) {
  __shared__ int s_m[NK];
  __shared__ int s_perm[NK];
  const int k = threadIdx.x;

  int first = -1, last = -1;
  for (int l = 0; l < LW; ++l) {
    const float w = W[k * LW + l];
    if (w != 0.0f) { if (first < 0) first = l; last = l; }
  }
  if (first < 0) { first = 124; last = 124; }
  const int lo = first >> 5, hi = (last >> 5) + 1;
  int M = max(4 - lo, hi - 4);
  M = min(max(M, 1), 4);          // taps centered -> kb window [4-M, 4+M)
  s_m[k] = M;
  __syncthreads();
  // deterministic rank (stable sort by M ascending)
  int pos = 0;
  for (int j = 0; j < NK; ++j) {
    const int Mj = s_m[j];
    pos += (Mj < M || (Mj == M && j < k)) ? 1 : 0;
  }
  s_perm[pos] = k;
  __syncthreads();

  perm[k]  = s_perm[k];
  biasP[k] = bias[s_perm[k]];
  if (k < 16) {
    int mM = 1;
    for (int j = 0; j < 16; ++j) mM = max(mM, s_m[s_perm[k * 16 + j]]);
    tileM[k] = mM;
  }
  for (int r = 0; r < NK; ++r) {
    const int src = s_perm[r];
    const float v = (k < LW) ? W[src * LW + k] : 0.0f;
    Wh[r * WHS + k] = (f16)v;
  }
}

// ---- main: 1 m-tile per wave, windowed kb, ring with compile-time slots ----
__global__ __launch_bounds__(THREADS, 2) void rocket_mfma(
    const float* __restrict__ x, const f16* __restrict__ Wh,
    const float* __restrict__ biasP, const int* __restrict__ tileM,
    float2* __restrict__ part) {
  __shared__ f16 xc[NCOPY * CPL];

  const int bc   = blockIdx.x;        // 0..255
  const int h    = blockIdx.y;        // t-half: nt in [h*63, h*63+63)
  const int tg   = blockIdx.z;        // tile group: tiles [tg*8, tg*8+8)
  const int tid  = threadIdx.x;
  const int wid  = tid >> 6;
  const int lane = tid & 63;
  const int l15  = lane & 15;
  const int lq   = lane >> 4;

  // stage 8 shifted f16 copies of the padded row
  const float* xrow = x + bc * TLEN;
  for (int q = tid * 4; q < NCOPY * CPWRITE; q += THREADS * 4) {
    const int cpy = q / CPWRITE;
    const int i   = q - cpy * CPWRITE;
    half4 v;
#pragma unroll
    for (int r = 0; r < 4; ++r) {
      const int j = i + r + cpy - PAD;
      v[r] = (j >= 0 && j < TLEN) ? (f16)xrow[j] : (f16)0.0f;
    }
    *(half4*)&xc[cpy * CPL + i] = v;
  }
  __syncthreads();

  // snake: SIMD s (wid&3) hosts tiles tg*8 + {s, 7-s}  (M-balanced)
  const int tile = tg * 8 + ((wid < 4) ? wid : (7 - (wid & 3)));
  const int M    = __builtin_amdgcn_readfirstlane(tileM[tile]);
  const int klo  = 4 - M, khi = 4 + M;

  // A fragments: af[kb], lane holds Wh[row = tile*16 + l15][kb*32 + 8*lq ..+7]
  half8 af[8];
#pragma unroll
  for (int kb = 0; kb < 8; ++kb)
    af[kb] = *(const half8*)&Wh[(tile * 16 + l15) * WHS + kb * 32 + 8 * lq];

  float thr[4];
#pragma unroll
  for (int r = 0; r < 4; ++r) thr[r] = -biasP[tile * 16 + lq * 4 + r];

  const int lane_e  = 8 * lq + l15;
  const int cpy     = l15 & 7;
  const int cpyBase = cpy * CPL + (lane_e - cpy);
  const int ntmax   = h ? 124 : 62;

  int cnt[4]; float mx[4];
#pragma unroll
  for (int r = 0; r < 4; ++r) { cnt[r] = 0; mx[r] = -INFINITY; }

  for (int p = 0; p < 2; ++p) {       // parity pass over this t-half
    const int nt0 = h * 63 + p;
    const int b0  = cpyBase + nt0 * 16;
    half8 R[8];
#pragma unroll
    for (int kb = 0; kb < 8; ++kb) R[kb] = *(const half8*)&xc[b0 + kb * 32];

    for (int it = 0; it < 4; ++it) {
#pragma unroll
      for (int ui = 0; ui < 8; ++ui) {
        const int u  = it * 8 + ui;
        const int nt = nt0 + 2 * u;
        f32x4 acc0 = (f32x4){0.0f, 0.0f, 0.0f, 0.0f};
        f32x4 acc1 = (f32x4){0.0f, 0.0f, 0.0f, 0.0f};
#pragma unroll
        for (int kb = 0; kb < 8; ++kb) {
          if (kb >= klo && kb < khi) {      // wave-uniform window test
            if (kb & 1) acc1 = __builtin_amdgcn_mfma_f32_16x16x32_f16(af[kb], R[(ui + kb) & 7], acc1, 0, 0, 0);
            else        acc0 = __builtin_amdgcn_mfma_f32_16x16x32_f16(af[kb], R[(ui + kb) & 7], acc0, 0, 0, 0);
          }
        }
        // slide: load frag(nt+2, khi-1) into slot (ui+khi)&7
        R[(ui + khi) & 7] = *(const half8*)&xc[b0 + 32 * u + 32 * khi];
        if (nt <= ntmax) {
#pragma unroll
          for (int r = 0; r < 4; ++r) {
            const float v = acc0[r] + acc1[r];
            cnt[r] += (v > thr[r]) ? 1 : 0;
            mx[r]   = fmaxf(mx[r], v);
          }
        }
      }
    }
  }

  // reduce over the 16 lanes sharing each k, write partial for this t-half
#pragma unroll
  for (int r = 0; r < 4; ++r) {
    float c0 = (float)cnt[r], m0 = mx[r];
#pragma unroll
    for (int s = 1; s < 16; s <<= 1) {
      c0 += __shfl_xor(c0, s, 16);
      m0  = fmaxf(m0, __shfl_xor(m0, s, 16));
    }
    if (l15 == 0) {
      const int ks = tile * 16 + lq * 4 + r;      // sorted index
      part[(h * NK + bc) * NK + ks] = make_float2(c0, m0);
    }
  }
}

// ---- combine the two t-halves, un-permute, finalize ----
__global__ __launch_bounds__(256) void combine(const float2* __restrict__ part,
                                               const float* __restrict__ biasP,
                                               const int* __restrict__ perm,
                                               float* __restrict__ out) {
  const int bc = blockIdx.x, ks = threadIdx.x;
  const float2 p0 = part[(0 * NK + bc) * NK + ks];
  const float2 p1 = part[(1 * NK + bc) * NK + ks];
  const int ko = perm[ks];
  float2 res;
  res.x = (p0.x + p1.x) * (1.0f / (float)TLEN);
  res.y = fmaxf(p0.y, p1.y) + biasP[ks];
  *(float2*)&out[bc * (2 * NK) + 2 * ko] = res;
}

extern "C" void kernel_launch(void* const* d_in, const int* in_sizes, int n_in,
                              void* d_out, int out_size, void* d_ws, size_t ws_size,
                              hipStream_t stream) {
  const float* x    = (const float*)d_in[0];   // (8,32,2000)
  const float* W    = (const float*)d_in[1];   // (256,249)
  const float* bias = (const float*)d_in[2];   // (256,)
  float* out = (float*)d_out;                  // (8,32,512)

  f16*    Wh    = (f16*)d_ws;
  float*  biasP = (float*)((char*)d_ws + WS_BIASP);
  int*    perm  = (int*)((char*)d_ws + WS_PERM);
  int*    tileM = (int*)((char*)d_ws + WS_TM);
  float2* partP = (float2*)((char*)d_ws + WS_PART);

  prep<<<1, 256, 0, stream>>>(W, bias, Wh, biasP, perm, tileM);
  rocket_mfma<<<dim3(256, 2, 2), THREADS, 0, stream>>>(x, Wh, biasP, tileM, partP);
  combine<<<256, 256, 0, stream>>>(partP, biasP, perm, out);
}

// Round 8
// 100.040 us; speedup vs baseline: 19.0344x; 19.0344x over previous
//
#include <hip/hip_runtime.h>
#include <math.h>

typedef _Float16 f16;
typedef _Float16 half4 __attribute__((ext_vector_type(4)));
typedef _Float16 half8 __attribute__((ext_vector_type(8)));
typedef float f32x4 __attribute__((ext_vector_type(4)));

#define NK 256
#define LW 249
#define WHS 256          // Wh row stride (f16, zero-padded)
#define TLEN 2000
#define PAD 124
#define NCOPY 8
#define CPL 2328         // elems/copy; dword stride 1164 == 12 mod 32 -> conflict-free b128
#define CPWRITE 2304
#define THREADS 512

// ws layout (bytes)
#define WS_BIASP (NK * WHS * 2)
#define WS_PERM  (WS_BIASP + NK * 4)
#define WS_TM    (WS_PERM + NK * 4)

// ---- prep: deterministic rank-sort rows by window size M, permuted f16 W ----
__global__ __launch_bounds__(256) void prep(const float* __restrict__ W,
                                            const float* __restrict__ bias,
                                            f16* __restrict__ Wh,
                                            float* __restrict__ biasP,
                                            int* __restrict__ perm,
                                            int* __restrict__ tileM) {
  __shared__ int s_m[NK];
  __shared__ int s_perm[NK];
  const int k = threadIdx.x;

  int first = -1, last = -1;
  for (int l = 0; l < LW; ++l) {
    const float w = W[k * LW + l];
    if (w != 0.0f) { if (first < 0) first = l; last = l; }
  }
  if (first < 0) { first = 124; last = 124; }
  const int lo = first >> 5, hi = (last >> 5) + 1;
  int M = max(4 - lo, hi - 4);
  M = min(max(M, 1), 4);          // taps centered -> kb window [4-M, 4+M)
  s_m[k] = M;
  __syncthreads();
  // deterministic rank (stable sort by M ascending)
  int pos = 0;
  for (int j = 0; j < NK; ++j) {
    const int Mj = s_m[j];
    pos += (Mj < M || (Mj == M && j < k)) ? 1 : 0;
  }
  s_perm[pos] = k;
  __syncthreads();

  perm[k]  = s_perm[k];
  biasP[k] = bias[s_perm[k]];
  if (k < 16) {
    int mM = 1;
    for (int j = 0; j < 16; ++j) mM = max(mM, s_m[s_perm[k * 16 + j]]);
    tileM[k] = mM;
  }
  for (int r = 0; r < NK; ++r) {
    const int src = s_perm[r];
    const float v = (k < LW) ? W[src * LW + k] : 0.0f;
    Wh[r * WHS + k] = (f16)v;
  }
}

// ---- per-wave templated loop: MFMA only on kb in [4-M, 4+M); ALL indices static ----
template <int M>
__device__ __forceinline__ void run_tile(const f16* xc, const f16* __restrict__ Wh,
                                         const float* __restrict__ biasP,
                                         const int* __restrict__ perm,
                                         float* __restrict__ out,
                                         int bc, int tile, int l15, int lq, int cpyBase) {
  constexpr int KLO = 4 - M;
  half8 af[2 * M];
#pragma unroll
  for (int a = 0; a < 2 * M; ++a)
    af[a] = *(const half8*)&Wh[(tile * 16 + l15) * WHS + (KLO + a) * 32 + 8 * lq];

  float thr[4];
#pragma unroll
  for (int r = 0; r < 4; ++r) thr[r] = -biasP[tile * 16 + lq * 4 + r];

  int cnt[4]; float mx[4];
#pragma unroll
  for (int r = 0; r < 4; ++r) { cnt[r] = 0; mx[r] = -INFINITY; }

  for (int p = 0; p < 2; ++p) {        // nt parity pass over full t-range
    const int b0 = cpyBase + p * 16;
    half8 R[8];
#pragma unroll
    for (int kb = 0; kb < 8; ++kb) R[kb] = *(const half8*)&xc[b0 + kb * 32];

    for (int it = 0; it < 8; ++it) {
#pragma unroll
      for (int ui = 0; ui < 8; ++ui) {
        const int u  = it * 8 + ui;
        const int nt = p + 2 * u;
        f32x4 acc0 = (f32x4){0.0f, 0.0f, 0.0f, 0.0f};
        f32x4 acc1 = (f32x4){0.0f, 0.0f, 0.0f, 0.0f};
#pragma unroll
        for (int a = 0; a < 2 * M; ++a) {
          const int kb = KLO + a;                       // compile-time
          const half8 b = R[(ui + kb) & 7];             // static slot
          if (a & 1) acc1 = __builtin_amdgcn_mfma_f32_16x16x32_f16(af[a], b, acc1, 0, 0, 0);
          else       acc0 = __builtin_amdgcn_mfma_f32_16x16x32_f16(af[a], b, acc0, 0, 0, 0);
        }
        R[ui] = *(const half8*)&xc[b0 + 32 * u + 256];  // static slot slide (dead data masked)
        if (nt <= 124) {                                // 2000 = 125*16: whole tile valid
#pragma unroll
          for (int r = 0; r < 4; ++r) {
            const float v = acc0[r] + acc1[r];
            cnt[r] += (v > thr[r]) ? 1 : 0;
            mx[r]   = fmaxf(mx[r], v);
          }
        }
      }
    }
  }

  // reduce over the 16 lanes sharing each k, un-permute, write final
#pragma unroll
  for (int r = 0; r < 4; ++r) {
    float c0 = (float)cnt[r], m0 = mx[r];
#pragma unroll
    for (int s = 1; s < 16; s <<= 1) {
      c0 += __shfl_xor(c0, s, 16);
      m0  = fmaxf(m0, __shfl_xor(m0, s, 16));
    }
    if (l15 == 0) {
      const int ko = perm[tile * 16 + lq * 4 + r];
      float2 res;
      res.x = c0 * (1.0f / (float)TLEN);
      res.y = m0 - thr[r];          // + bias
      *(float2*)&out[bc * (2 * NK) + 2 * ko] = res;
    }
  }
}

__global__ __launch_bounds__(THREADS, 4) void rocket_mfma(
    const float* __restrict__ x, const f16* __restrict__ Wh,
    const float* __restrict__ biasP, const int* __restrict__ perm,
    const int* __restrict__ tileM, float* __restrict__ out) {
  __shared__ f16 xc[NCOPY * CPL];

  const int bc   = blockIdx.x;        // 0..255
  const int tg   = blockIdx.y;        // 0..1
  const int tid  = threadIdx.x;
  const int wid  = tid >> 6;
  const int lane = tid & 63;
  const int l15  = lane & 15;
  const int lq   = lane >> 4;

  // stage 8 shifted f16 copies of the padded row
  const float* xrow = x + bc * TLEN;
  for (int q = tid * 4; q < NCOPY * CPWRITE; q += THREADS * 4) {
    const int cpy = q / CPWRITE;
    const int i   = q - cpy * CPWRITE;
    half4 v;
#pragma unroll
    for (int r = 0; r < 4; ++r) {
      const int j = i + r + cpy - PAD;
      v[r] = (j >= 0 && j < TLEN) ? (f16)xrow[j] : (f16)0.0f;
    }
    *(half4*)&xc[cpy * CPL + i] = v;
  }
  __syncthreads();

  // paired tile assignment: SIMD s gets sorted tiles {2s+tg, 15-2s-tg}
  // (one small-M + one large-M per SIMD; the two tg blocks are disjoint)
  const int s4   = wid & 3;
  const int tile = (wid < 4) ? (2 * s4 + tg) : (15 - 2 * s4 - tg);
  const int M    = __builtin_amdgcn_readfirstlane(tileM[tile]);

  const int lane_e  = 8 * lq + l15;
  const int cpy     = l15 & 7;
  const int cpyBase = cpy * CPL + (lane_e - cpy);

  switch (M) {
    case 1:  run_tile<1>(xc, Wh, biasP, perm, out, bc, tile, l15, lq, cpyBase); break;
    case 2:  run_tile<2>(xc, Wh, biasP, perm, out, bc, tile, l15, lq, cpyBase); break;
    case 3:  run_tile<3>(xc, Wh, biasP, perm, out, bc, tile, l15, lq, cpyBase); break;
    default: run_tile<4>(xc, Wh, biasP, perm, out, bc, tile, l15, lq, cpyBase); break;
  }
}

extern "C" void kernel_launch(void* const* d_in, const int* in_sizes, int n_in,
                              void* d_out, int out_size, void* d_ws, size_t ws_size,
                              hipStream_t stream) {
  const float* x    = (const float*)d_in[0];   // (8,32,2000)
  const float* W    = (const float*)d_in[1];   // (256,249)
  const float* bias = (const float*)d_in[2];   // (256,)
  float* out = (float*)d_out;                  // (8,32,512)

  f16*   Wh    = (f16*)d_ws;
  float* biasP = (float*)((char*)d_ws + WS_BIASP);
  int*   perm  = (int*)((char*)d_ws + WS_PERM);
  int*   tileM = (int*)((char*)d_ws + WS_TM);

  prep<<<1, 256, 0, stream>>>(W, bias, Wh, biasP, perm, tileM);
  rocket_mfma<<<dim3(256, 2), THREADS, 0, stream>>>(x, Wh, biasP, perm, tileM, out);
}

// Round 9
// 58.494 us; speedup vs baseline: 32.5537x; 1.7103x over previous
//
#include <hip/hip_runtime.h>
#include <math.h>

typedef _Float16 f16;
typedef _Float16 half4 __attribute__((ext_vector_type(4)));
typedef _Float16 half8 __attribute__((ext_vector_type(8)));
typedef float f32x4 __attribute__((ext_vector_type(4)));

#define NK 256
#define LW 249
#define WHS 256          // Wh row stride (f16, zero-padded)
#define TLEN 2000
#define PAD 124
#define NCOPY 8
#define CPL 2328         // elems/copy; dword stride 1164 == 12 mod 32 -> conflict-free b128
#define CPWRITE 2304
#define THREADS 512

// ws layout (bytes)
#define WS_BIASP (NK * WHS * 2)
#define WS_PERM  (WS_BIASP + NK * 4)
#define WS_TM    (WS_PERM + NK * 4)
#define WS_MROW  (WS_TM + 64)

// ---- prep 1: per-row tap extent -> window size M (one wave per row) ----
__global__ __launch_bounds__(64) void scan_extents(const float* __restrict__ W,
                                                   int* __restrict__ Mrow) {
  const int k = blockIdx.x, lane = threadIdx.x;
  int mn = 1 << 30, mx = -1;
  for (int l = lane; l < LW; l += 64) {
    if (W[k * LW + l] != 0.0f) { mn = min(mn, l); mx = max(mx, l); }
  }
#pragma unroll
  for (int s = 32; s; s >>= 1) {
    mn = min(mn, __shfl_xor(mn, s, 64));
    mx = max(mx, __shfl_xor(mx, s, 64));
  }
  if (lane == 0) {
    if (mx < 0) { mn = 124; mx = 124; }     // all-zero row -> center
    const int lo = mn >> 5, hi = (mx >> 5) + 1;
    int M = max(4 - lo, hi - 4);
    Mrow[k] = min(max(M, 1), 4);            // taps centered -> kb window [4-M, 4+M)
  }
}

// ---- prep 2: deterministic rank-sort by M, perm/bias/tileM (tiny, 1 block) ----
__global__ __launch_bounds__(256) void rank_rows(const int* __restrict__ Mrow,
                                                 const float* __restrict__ bias,
                                                 float* __restrict__ biasP,
                                                 int* __restrict__ perm,
                                                 int* __restrict__ tileM) {
  __shared__ int s_m[NK];
  __shared__ int s_perm[NK];
  const int k = threadIdx.x;
  s_m[k] = Mrow[k];
  __syncthreads();
  const int M = s_m[k];
  int pos = 0;
  for (int j = 0; j < NK; ++j) {
    const int Mj = s_m[j];
    pos += (Mj < M || (Mj == M && j < k)) ? 1 : 0;   // stable rank
  }
  s_perm[pos] = k;
  __syncthreads();
  perm[k]  = s_perm[k];
  biasP[k] = bias[s_perm[k]];
  if (k < 16) {
    int mM = 1;
    for (int j = 0; j < 16; ++j) mM = max(mM, s_m[s_perm[k * 16 + j]]);
    tileM[k] = mM;
  }
}

// ---- prep 3: permuted f16 weights, one block per dest row (coalesced) ----
__global__ __launch_bounds__(256) void permute_W(const float* __restrict__ W,
                                                 const int* __restrict__ perm,
                                                 f16* __restrict__ Wh) {
  const int r = blockIdx.x, l = threadIdx.x;
  const int src = perm[r];
  Wh[r * WHS + l] = (l < LW) ? (f16)W[src * LW + l] : (f16)0.0f;
}

// ---- per-wave templated loop: MFMA only on kb in [4-M, 4+M); ALL indices static ----
template <int M>
__device__ __forceinline__ void run_tile(const f16* xc, const f16* __restrict__ Wh,
                                         const float* __restrict__ biasP,
                                         const int* __restrict__ perm,
                                         float* __restrict__ out,
                                         int bc, int tile, int l15, int lq, int cpyBase) {
  constexpr int KLO = 4 - M;
  half8 af[2 * M];
#pragma unroll
  for (int a = 0; a < 2 * M; ++a)
    af[a] = *(const half8*)&Wh[(tile * 16 + l15) * WHS + (KLO + a) * 32 + 8 * lq];

  float thr[4];
#pragma unroll
  for (int r = 0; r < 4; ++r) thr[r] = -biasP[tile * 16 + lq * 4 + r];

  int cnt[4]; float mx[4];
#pragma unroll
  for (int r = 0; r < 4; ++r) { cnt[r] = 0; mx[r] = -INFINITY; }

  for (int p = 0; p < 2; ++p) {        // nt parity pass over full t-range
    const int b0 = cpyBase + p * 16;
    half8 R[8];
#pragma unroll
    for (int kb = 0; kb < 8; ++kb) R[kb] = *(const half8*)&xc[b0 + kb * 32];

    for (int it = 0; it < 8; ++it) {
#pragma unroll
      for (int ui = 0; ui < 8; ++ui) {
        const int u  = it * 8 + ui;
        const int nt = p + 2 * u;
        f32x4 acc0 = (f32x4){0.0f, 0.0f, 0.0f, 0.0f};
        f32x4 acc1 = (f32x4){0.0f, 0.0f, 0.0f, 0.0f};
#pragma unroll
        for (int a = 0; a < 2 * M; ++a) {
          const int kb = KLO + a;                       // compile-time
          const half8 b = R[(ui + kb) & 7];             // static slot
          if (a & 1) acc1 = __builtin_amdgcn_mfma_f32_16x16x32_f16(af[a], b, acc1, 0, 0, 0);
          else       acc0 = __builtin_amdgcn_mfma_f32_16x16x32_f16(af[a], b, acc0, 0, 0, 0);
        }
        R[ui] = *(const half8*)&xc[b0 + 32 * u + 256];  // static slot slide (dead data masked)
        if (nt <= 124) {                                // 2000 = 125*16: whole tile valid
#pragma unroll
          for (int r = 0; r < 4; ++r) {
            const float v = acc0[r] + acc1[r];
            cnt[r] += (v > thr[r]) ? 1 : 0;
            mx[r]   = fmaxf(mx[r], v);
          }
        }
      }
    }
  }

  // reduce over the 16 lanes sharing each k, un-permute, write final
#pragma unroll
  for (int r = 0; r < 4; ++r) {
    float c0 = (float)cnt[r], m0 = mx[r];
#pragma unroll
    for (int s = 1; s < 16; s <<= 1) {
      c0 += __shfl_xor(c0, s, 16);
      m0  = fmaxf(m0, __shfl_xor(m0, s, 16));
    }
    if (l15 == 0) {
      const int ko = perm[tile * 16 + lq * 4 + r];
      float2 res;
      res.x = c0 * (1.0f / (float)TLEN);
      res.y = m0 - thr[r];          // + bias
      *(float2*)&out[bc * (2 * NK) + 2 * ko] = res;
    }
  }
}

__global__ __launch_bounds__(THREADS, 4) void rocket_mfma(
    const float* __restrict__ x, const f16* __restrict__ Wh,
    const float* __restrict__ biasP, const int* __restrict__ perm,
    const int* __restrict__ tileM, float* __restrict__ out) {
  __shared__ f16 xc[NCOPY * CPL];

  const int bc   = blockIdx.x;        // 0..255
  const int tg   = blockIdx.y;        // 0..1
  const int tid  = threadIdx.x;
  const int wid  = tid >> 6;
  const int lane = tid & 63;
  const int l15  = lane & 15;
  const int lq   = lane >> 4;

  // stage 8 shifted f16 copies of the padded row
  const float* xrow = x + bc * TLEN;
  for (int q = tid * 4; q < NCOPY * CPWRITE; q += THREADS * 4) {
    const int cpy = q / CPWRITE;
    const int i   = q - cpy * CPWRITE;
    half4 v;
#pragma unroll
    for (int r = 0; r < 4; ++r) {
      const int j = i + r + cpy - PAD;
      v[r] = (j >= 0 && j < TLEN) ? (f16)xrow[j] : (f16)0.0f;
    }
    *(half4*)&xc[cpy * CPL + i] = v;
  }
  __syncthreads();

  // paired tile assignment: SIMD s gets sorted tiles {2s+tg, 15-2s-tg}
  const int s4   = wid & 3;
  const int tile = (wid < 4) ? (2 * s4 + tg) : (15 - 2 * s4 - tg);
  const int M    = __builtin_amdgcn_readfirstlane(tileM[tile]);

  const int lane_e  = 8 * lq + l15;
  const int cpy     = l15 & 7;
  const int cpyBase = cpy * CPL + (lane_e - cpy);

  switch (M) {
    case 1:  run_tile<1>(xc, Wh, biasP, perm, out, bc, tile, l15, lq, cpyBase); break;
    case 2:  run_tile<2>(xc, Wh, biasP, perm, out, bc, tile, l15, lq, cpyBase); break;
    case 3:  run_tile<3>(xc, Wh, biasP, perm, out, bc, tile, l15, lq, cpyBase); break;
    default: run_tile<4>(xc, Wh, biasP, perm, out, bc, tile, l15, lq, cpyBase); break;
  }
}

extern "C" void kernel_launch(void* const* d_in, const int* in_sizes, int n_in,
                              void* d_out, int out_size, void* d_ws, size_t ws_size,
                              hipStream_t stream) {
  const float* x    = (const float*)d_in[0];   // (8,32,2000)
  const float* W    = (const float*)d_in[1];   // (256,249)
  const float* bias = (const float*)d_in[2];   // (256,)
  float* out = (float*)d_out;                  // (8,32,512)

  f16*   Wh    = (f16*)d_ws;
  float* biasP = (float*)((char*)d_ws + WS_BIASP);
  int*   perm  = (int*)((char*)d_ws + WS_PERM);
  int*   tileM = (int*)((char*)d_ws + WS_TM);
  int*   Mrow  = (int*)((char*)d_ws + WS_MROW);

  scan_extents<<<NK, 64, 0, stream>>>(W, Mrow);
  rank_rows<<<1, 256, 0, stream>>>(Mrow, bias, biasP, perm, tileM);
  permute_W<<<NK, 256, 0, stream>>>(W, perm, Wh);
  rocket_mfma<<<dim3(256, 2), THREADS, 0, stream>>>(x, Wh, biasP, perm, tileM, out);
}